// Round 7
// baseline (4442.047 us; speedup 1.0000x reference)
//
#include <hip/hip_runtime.h>
#include <stdint.h>

#define SEQ 512
#define HID 512
#define GATES 2048
#define IN0 1088
#define IN1 1024
#define MLPH 100

// ---------------- zero (sync slots) ----------------
__global__ void zero_kernel(uint4* __restrict__ p, int n) {
  int i = blockIdx.x * blockDim.x + threadIdx.x;
  uint4 z = {0u, 0u, 0u, 0u};
  if (i < n) p[i] = z;
}

// ---------------- embedding gather + concat ----------------
__global__ __launch_bounds__(256) void embed_kernel(
    const int* __restrict__ widx, const int* __restrict__ pidx,
    const float* __restrict__ wemb, const float* __restrict__ pemb,
    float* __restrict__ out) {
  int t = blockIdx.x, tid = threadIdx.x;
  const float4* wsrc = (const float4*)(wemb + (size_t)widx[t] * 1024);
  float4* dst = (float4*)(out + (size_t)t * IN0);
  dst[tid] = wsrc[tid];                       // 256 float4 = 1024 floats
  if (tid < 16) {
    const float4* psrc = (const float4*)(pemb + (size_t)pidx[t] * 64);
    dst[256 + tid] = psrc[tid];               // 64 floats
  }
}

// ---------------- compiler-proof double exp: range-reduced Taylor ----------------
__device__ __forceinline__ double exp_d(double x) {
  const double LOG2E = 1.4426950408889634074;
  const double LN2HI = 6.93147180369123816490e-01;
  const double LN2LO = 1.90821492927058770002e-10;
  double t = x * LOG2E;
  double n = floor(t + 0.5);
  double r = x - n * LN2HI;
  r = r - n * LN2LO;
  double p = 2.50521083854417187751e-08;   // 1/11!
  p = p * r + 2.75573192239858906526e-07;  // 1/10!
  p = p * r + 2.75573192239858925110e-06;  // 1/9!
  p = p * r + 2.48015873015873015873e-05;  // 1/8!
  p = p * r + 1.98412698412698412698e-04;  // 1/7!
  p = p * r + 1.38888888888888888889e-03;  // 1/6!
  p = p * r + 8.33333333333333333333e-03;  // 1/5!
  p = p * r + 4.16666666666666666667e-02;  // 1/4!
  p = p * r + 1.66666666666666666667e-01;  // 1/3!
  p = p * r + 0.5;
  p = p * r + 1.0;
  p = p * r + 1.0;
  long long ni = (long long)n;
  double s = __longlong_as_double((unsigned long long)(ni + 1023) << 52);
  return p * s;
}

// ---------------- xw GEMM: fp32 in/out, fp64 K-accumulation (deterministic) ----------------
__global__ __launch_bounds__(256) void gemm_facc(
    const float* __restrict__ A, const float* __restrict__ Bt,
    const float* __restrict__ bias, float* __restrict__ C,
    int M, int N, int K) {
  int ntiles = N >> 6;
  int bid = blockIdx.x;
  int mt = bid / ntiles, nt = bid - mt * ntiles;

  __shared__ float As[16][68];
  __shared__ float Bs[16][68];
  int tid = threadIdx.x;
  int tx = tid & 15, ty = tid >> 4;
  int m0 = mt << 6, n0 = nt << 6;

  int lk4 = tid & 3;
  int lrow = tid >> 2;
  const float* Ap = A + (size_t)(m0 + lrow) * K + lk4 * 4;
  const float* Bp = Bt + (size_t)(n0 + lrow) * K + lk4 * 4;

  double acc[4][4];
#pragma unroll
  for (int i = 0; i < 4; ++i)
#pragma unroll
    for (int j = 0; j < 4; ++j) acc[i][j] = 0.0;

  for (int kk = 0; kk < K; kk += 16) {
    float4 av = *(const float4*)(Ap + kk);
    float4 bv = *(const float4*)(Bp + kk);
    int kbase = lk4 * 4;
    As[kbase + 0][lrow] = av.x; As[kbase + 1][lrow] = av.y;
    As[kbase + 2][lrow] = av.z; As[kbase + 3][lrow] = av.w;
    Bs[kbase + 0][lrow] = bv.x; Bs[kbase + 1][lrow] = bv.y;
    Bs[kbase + 2][lrow] = bv.z; Bs[kbase + 3][lrow] = bv.w;
    __syncthreads();
#pragma unroll
    for (int k = 0; k < 16; ++k) {
      float a[4], b[4];
      *(float4*)a = *(const float4*)&As[k][ty << 2];
      *(float4*)b = *(const float4*)&Bs[k][tx << 2];
#pragma unroll
      for (int i = 0; i < 4; ++i)
#pragma unroll
        for (int j = 0; j < 4; ++j) acc[i][j] += (double)a[i] * (double)b[j];
    }
    __syncthreads();
  }

#pragma unroll
  for (int i = 0; i < 4; ++i) {
    int mrow = m0 + (ty << 2) + i;
#pragma unroll
    for (int j = 0; j < 4; ++j) {
      int ncol = n0 + (tx << 2) + j;
      C[(size_t)mrow * N + ncol] = (float)(acc[i][j] + (double)bias[ncol]);
    }
  }
}

// ---------------- MLP projection stage 1: per-K-chunk partials, fp64 accumulation ----------------
__global__ __launch_bounds__(256) void gemm_pd_kernel(
    const float* __restrict__ A, const float* __restrict__ Bt,
    float* __restrict__ Cpart, int M, int N, int K, int ldb, int kSplit) {
  int ntiles = (N + 63) >> 6;
  int mtiles = M >> 6;
  int tilesPer = ntiles * mtiles;
  int bid = blockIdx.x;
  int kchunk = bid / tilesPer;
  int rem = bid - kchunk * tilesPer;
  int mt = rem / ntiles, nt = rem - mt * ntiles;
  int kLen = K / kSplit;
  int k0 = kchunk * kLen;

  __shared__ float As[16][68];
  __shared__ float Bs[16][68];
  int tid = threadIdx.x;
  int tx = tid & 15, ty = tid >> 4;
  int m0 = mt << 6, n0 = nt << 6;

  int lk4 = tid & 3;
  int lrow = tid >> 2;
  const float* Ap = A + (size_t)(m0 + lrow) * K + k0 + lk4 * 4;
  const float* Bp = Bt + (size_t)(n0 + lrow) * ldb + k0 + lk4 * 4;
  bool bvalid = (n0 + lrow) < N;

  double acc[4][4];
#pragma unroll
  for (int i = 0; i < 4; ++i)
#pragma unroll
    for (int j = 0; j < 4; ++j) acc[i][j] = 0.0;

  for (int kk = 0; kk < kLen; kk += 16) {
    float4 av = *(const float4*)(Ap + kk);
    float4 bv;
    if (bvalid) bv = *(const float4*)(Bp + kk);
    else { bv.x = bv.y = bv.z = bv.w = 0.f; }
    int kbase = lk4 * 4;
    As[kbase + 0][lrow] = av.x; As[kbase + 1][lrow] = av.y;
    As[kbase + 2][lrow] = av.z; As[kbase + 3][lrow] = av.w;
    Bs[kbase + 0][lrow] = bv.x; Bs[kbase + 1][lrow] = bv.y;
    Bs[kbase + 2][lrow] = bv.z; Bs[kbase + 3][lrow] = bv.w;
    __syncthreads();
#pragma unroll
    for (int k = 0; k < 16; ++k) {
      float a[4], b[4];
      *(float4*)a = *(const float4*)&As[k][ty << 2];
      *(float4*)b = *(const float4*)&Bs[k][tx << 2];
#pragma unroll
      for (int i = 0; i < 4; ++i)
#pragma unroll
        for (int j = 0; j < 4; ++j) acc[i][j] += (double)a[i] * (double)b[j];
    }
    __syncthreads();
  }

#pragma unroll
  for (int i = 0; i < 4; ++i) {
    int mrow = m0 + (ty << 2) + i;
#pragma unroll
    for (int j = 0; j < 4; ++j) {
      int ncol = n0 + (tx << 2) + j;
      if (ncol < N)
        Cpart[((size_t)kchunk * M + mrow) * N + ncol] = (float)acc[i][j];
    }
  }
}

// ---------------- MLP projection stage 2: fixed-order reduce over kSplit chunks ----------------
__global__ __launch_bounds__(256) void mlp_reduce_kernel(
    const float* __restrict__ Psh, const float* __restrict__ Psm,
    const float* __restrict__ b1, float* __restrict__ sh, float* __restrict__ sm) {
  int idx = blockIdx.x * 256 + threadIdx.x;
  const int HALF = SEQ * MLPH;  // 51200
  if (idx < HALF) {
    float s = 0.f;
#pragma unroll
    for (int c = 0; c < 8; ++c) s += Psh[(size_t)c * HALF + idx];
    sh[idx] = s;
  } else if (idx < 2 * HALF) {
    int j = idx - HALF;
    float s = 0.f;
#pragma unroll
    for (int c = 0; c < 8; ++c) s += Psm[(size_t)c * HALF + j];
    sm[j] = s + b1[j % MLPH];
  }
}

// ---------------- biLSTM layer scan (R7: 64 WGs — contention cut) ----------------
// grid = 64 WGs x 256 threads. WG 0..31 forward, 32..63 backward; each owns 16 h-rows.
// W tile (64 gate rows x 512) fp32 in LDS (128 KB), loaded once. h exchanged as
// fp32 {epoch|value} u64 slots, double-buffered. Poll re-loads only unmatched
// slots (cuts steady-state retry fetch traffic). Arithmetic bit-identical to R6:
// same 16-col interleaved partial grouping {k*128+cg*4}, same fp64 reduce order,
// same exp_d gate tail, fp64 c-state.
__global__ __launch_bounds__(256, 1) void scan_kernel(
    const float* __restrict__ whh_f, const float* __restrict__ whh_b,
    const float* __restrict__ xw_f, const float* __restrict__ xw_b,
    float* __restrict__ hout, unsigned long long* __restrict__ slots) {
  int wg = blockIdx.x;
  int dir = wg >> 5;
  int lw = wg & 31;
  int r0 = lw << 4;                 // first owned h row (16 rows)
  const float* whh = dir ? whh_b : whh_f;
  const float* xw = dir ? xw_b : xw_f;
  unsigned long long* slotbase = slots + (size_t)dir * 1024;  // [buf2][512]

  int tid = threadIdx.x;
  int cg = tid & 31;                // col group
  int rg = tid >> 5;                // row group 0..7 (8 rows each)

  __shared__ __align__(16) float Wl[64][512];   // 128 KB
  __shared__ __align__(16) float hl[512];       // 2 KB
  __shared__ float part[64][33];                // 8.4 KB

  // load W tile: local row r (0..63) -> global row (r>>4)*512 + r0 + (r&15)
  {
    float4* Wl4 = (float4*)&Wl[0][0];
#pragma unroll
    for (int i = 0; i < 32; ++i) {
      int fid = i * 256 + tid;        // 0..8191 float4s
      int row = fid >> 7;             // 0..63
      int c4 = fid & 127;
      int grow = ((row >> 4) << 9) + r0 + (row & 15);
      Wl4[row * 128 + c4] = *(const float4*)(whh + (size_t)grow * 512 + c4 * 4);
    }
  }
  __syncthreads();

  double cstate = 0.0;  // live in lanes 0..15 of wave 0

  for (int s = 0; s < SEQ; ++s) {
    int t = dir ? (SEQ - 1 - s) : s;

    // xw prefetch: lane j<64 takes gate row j (gate=j>>4, idx=j&15) — overlaps poll
    float xwv = 0.f;
    if (tid < 64)
      xwv = xw[(size_t)t * GATES + ((tid >> 4) << 9) + r0 + (tid & 15)];

    // obtain h_{s-1}: wave 1 polls all 512 slots (8 per lane), writes hl.
    // Only not-yet-matched slots are re-loaded on retry.
    if (s == 0) {
      for (int i = tid; i < 512; i += 256) hl[i] = 0.f;
    } else if ((tid >> 6) == 1) {
      unsigned long long* sb = slotbase + (size_t)((s + 1) & 1) * 512;
      unsigned long long expect = (unsigned long long)s;
      int lane = tid & 63;
      int base = lane * 8;
      unsigned long long v[8];
      bool done[8];
#pragma unroll
      for (int u = 0; u < 8; ++u) done[u] = false;
      bool ok;
      do {
        ok = true;
#pragma unroll
        for (int u = 0; u < 8; ++u) {
          if (!done[u]) {
            unsigned long long vv =
                __hip_atomic_load(&sb[base + u], __ATOMIC_RELAXED, __HIP_MEMORY_SCOPE_AGENT);
            if ((vv >> 32) == expect) { v[u] = vv; done[u] = true; }
            else ok = false;
          }
        }
      } while (!ok);
      float4 f0, f1;
      f0.x = __uint_as_float((unsigned)v[0]); f0.y = __uint_as_float((unsigned)v[1]);
      f0.z = __uint_as_float((unsigned)v[2]); f0.w = __uint_as_float((unsigned)v[3]);
      f1.x = __uint_as_float((unsigned)v[4]); f1.y = __uint_as_float((unsigned)v[5]);
      f1.z = __uint_as_float((unsigned)v[6]); f1.w = __uint_as_float((unsigned)v[7]);
      float4* hl4 = (float4*)hl;
      hl4[lane * 2] = f0;
      hl4[lane * 2 + 1] = f1;
    }
    __syncthreads();  // B1

    // matvec: thread (cg,rg): 8 rows, 16 cols {k*128 + cg*4 .. +3, k=0..3}
    // (same column grouping as R6 -> bit-identical partials)
    {
      const float4* hl4c = (const float4*)hl;
      float4 hv0 = hl4c[cg];
      float4 hv1 = hl4c[32 + cg];
      float4 hv2 = hl4c[64 + cg];
      float4 hv3 = hl4c[96 + cg];
      const float4* Wl4c = (const float4*)&Wl[0][0];
#pragma unroll
      for (int rr = 0; rr < 8; ++rr) {
        int r = (rg << 3) + rr;
        const float4* wrow = Wl4c + r * 128;
        float4 w0 = wrow[cg], w1 = wrow[32 + cg], w2 = wrow[64 + cg], w3 = wrow[96 + cg];
        float a = w0.x * hv0.x + w0.y * hv0.y + w0.z * hv0.z + w0.w * hv0.w
                + w1.x * hv1.x + w1.y * hv1.y + w1.z * hv1.z + w1.w * hv1.w
                + w2.x * hv2.x + w2.y * hv2.y + w2.z * hv2.z + w2.w * hv2.w
                + w3.x * hv3.x + w3.y * hv3.y + w3.z * hv3.z + w3.w * hv3.w;
        part[r][cg] = a;
      }
    }
    __syncthreads();  // B2

    // wave 0 lanes 0..63: fp64 fixed-order reduce; per-lane exp_d; gather; gates
    if (tid < 64) {
      double z = (double)xwv;
#pragma unroll
      for (int g = 0; g < 32; ++g) z += (double)part[tid][g];
      double ev = ((tid >> 4) == 2) ? exp_d(2.0 * z) : exp_d(-z);
      // lane j<16 needs: e_i (lane j), e_f (j+16), e_g (j+32), e_o (j+48)
      double e_f = __shfl(ev, tid + 16);
      double e_g = __shfl(ev, tid + 32);
      double e_o = __shfl(ev, tid + 48);
      if (tid < 16) {
        double ig = 1.0 / (1.0 + ev);
        double fg = 1.0 / (1.0 + e_f);
        double og = 1.0 / (1.0 + e_o);
        double gg = 1.0 - 2.0 / (e_g + 1.0);       // tanh(z_g)
        cstate = fg * cstate + ig * gg;
        double e2c = exp_d(2.0 * cstate);
        double hd = og * (1.0 - 2.0 / (e2c + 1.0)); // og * tanh(c)
        float h = (float)hd;
        // publish FIRST (leads the store queue), hout after
        unsigned long long pub =
            (((unsigned long long)(s + 1)) << 32) | (unsigned long long)__float_as_uint(h);
        __hip_atomic_store(&slotbase[(size_t)(s & 1) * 512 + r0 + tid], pub,
                           __ATOMIC_RELAXED, __HIP_MEMORY_SCOPE_AGENT);
        hout[(size_t)t * IN1 + dir * 512 + r0 + tid] = h;
      }
    }
    // no trailing barrier: hl(s+1) poll-writes happen only after B2(s)
  }
}

// ---------------- pairwise MLP score + column softmax ----------------
#define SCH 128
__global__ __launch_bounds__(256) void score_kernel(
    const float* __restrict__ sh, const float* __restrict__ smb,
    const float* __restrict__ W2v, const float* __restrict__ b2,
    float* __restrict__ out) {
  int m = blockIdx.x;
  int tid = threadIdx.x;
  __shared__ float smv[MLPH];
  __shared__ float w2s[MLPH];
  __shared__ float shc[SCH][101];
  __shared__ float sbuf[512];
  __shared__ float rbuf[256];

  if (tid < MLPH) {
    smv[tid] = smb[(size_t)m * MLPH + tid];
    w2s[tid] = W2v[tid];
  }
  __syncthreads();

  int row = tid >> 1, half = tid & 1;
  float bb = b2[0];
  for (int ch = 0; ch < 4; ++ch) {
    const float* src = sh + (size_t)ch * SCH * MLPH;
    for (int i = tid; i < SCH * MLPH; i += 256) {
      int r = i / MLPH, c = i - r * MLPH;
      shc[r][c] = src[i];
    }
    __syncthreads();
    float acc = 0.f;
#pragma unroll
    for (int k = 0; k < 50; ++k) {
      int kk = half * 50 + k;
      float x = shc[row][kk] + smv[kk];
      float e = __expf(x + x);
      float th = 1.f - 2.f / (e + 1.f);
      acc += w2s[kk] * th;
    }
    acc += __shfl_xor(acc, 1);
    if (half == 0) sbuf[ch * SCH + row] = acc + bb;
    __syncthreads();
  }

  float v0 = sbuf[tid], v1 = sbuf[tid + 256];
  rbuf[tid] = fmaxf(v0, v1);
  __syncthreads();
  for (int off = 128; off > 0; off >>= 1) {
    if (tid < off) rbuf[tid] = fmaxf(rbuf[tid], rbuf[tid + off]);
    __syncthreads();
  }
  float mx = rbuf[0];
  __syncthreads();
  float e0 = __expf(v0 - mx), e1 = __expf(v1 - mx);
  rbuf[tid] = e0 + e1;
  __syncthreads();
  for (int off = 128; off > 0; off >>= 1) {
    if (tid < off) rbuf[tid] += rbuf[tid + off];
    __syncthreads();
  }
  float inv = 1.f / rbuf[0];
  out[(size_t)tid * 512 + m] = e0 * inv;
  out[(size_t)(tid + 256) * 512 + m] = e1 * inv;
}

// ---------------- launch ----------------
extern "C" void kernel_launch(void* const* d_in, const int* in_sizes, int n_in,
                              void* d_out, int out_size, void* d_ws, size_t ws_size,
                              hipStream_t stream) {
  const int* widx = (const int*)d_in[0];
  const int* pidx = (const int*)d_in[1];
  const float* wemb = (const float*)d_in[2];
  const float* pemb = (const float*)d_in[3];
  const float* wih0f = (const float*)d_in[4];
  const float* whh0f = (const float*)d_in[5];
  const float* b0f = (const float*)d_in[6];
  const float* wih0b = (const float*)d_in[7];
  const float* whh0b = (const float*)d_in[8];
  const float* b0b = (const float*)d_in[9];
  const float* wih1f = (const float*)d_in[10];
  const float* whh1f = (const float*)d_in[11];
  const float* b1f = (const float*)d_in[12];
  const float* wih1b = (const float*)d_in[13];
  const float* whh1b = (const float*)d_in[14];
  const float* b1b = (const float*)d_in[15];
  const float* W1 = (const float*)d_in[16];
  const float* b1v = (const float*)d_in[17];
  const float* W2 = (const float*)d_in[18];
  const float* b2 = (const float*)d_in[19];
  float* out = (float*)d_out;

  // ---- workspace layout: 18.53 MB (unchanged from R6) ----
  float* ws = (float*)d_ws;
  float* embeds = ws;                          // 557,056
  float* xwf = embeds + 557056;                // 1,048,576
  float* xwb = xwf + 1048576;                  // 1,048,576
  float* h0 = xwb + 1048576;                   // 524,288
  float* h1 = h0 + 524288;                     // 524,288
  float* Psh = h1 + 524288;                    // 409,600
  float* Psm = Psh + 409600;                   // 409,600
  float* shb = Psm + 409600;                   // 51,200
  float* smb = shb + 51200;                    // 51,200
  unsigned long long* slots0 = (unsigned long long*)(smb + 51200);  // 2048 u64
  unsigned long long* slots1 = slots0 + 2048;                       // 2048 u64
  size_t total_bytes = (size_t)4624384 * 4 + 4096ull * 8;
  if (ws_size < total_bytes) return;

  // zero sync slots (4096 u64 = 32 KB)
  zero_kernel<<<8, 256, 0, stream>>>((uint4*)slots0, 4096 * 8 / 16);

  embed_kernel<<<SEQ, 256, 0, stream>>>(widx, pidx, wemb, pemb, embeds);

  // layer-0 input projections: [512,1088] @ [2048,1088]^T (fp64 accum, fp32 store)
  gemm_facc<<<8 * 32, 256, 0, stream>>>(embeds, wih0f, b0f, xwf, SEQ, GATES, IN0);
  gemm_facc<<<8 * 32, 256, 0, stream>>>(embeds, wih0b, b0b, xwb, SEQ, GATES, IN0);

  scan_kernel<<<64, 256, 0, stream>>>(whh0f, whh0b, xwf, xwb, h0, slots0);

  // layer-1 input projections: [512,1024] @ [2048,1024]^T
  gemm_facc<<<8 * 32, 256, 0, stream>>>(h0, wih1f, b1f, xwf, SEQ, GATES, IN1);
  gemm_facc<<<8 * 32, 256, 0, stream>>>(h0, wih1b, b1b, xwb, SEQ, GATES, IN1);

  scan_kernel<<<64, 256, 0, stream>>>(whh1f, whh1b, xwf, xwb, h1, slots1);

  // MLP projections: deterministic split-K=8, fp64-accumulated partials + fixed-order reduce
  gemm_pd_kernel<<<8 * 8 * 2, 256, 0, stream>>>(h1, W1, Psh, SEQ, MLPH, IN1, 2048, 8);
  gemm_pd_kernel<<<8 * 8 * 2, 256, 0, stream>>>(h1, W1 + 1024, Psm, SEQ, MLPH, IN1, 2048, 8);
  mlp_reduce_kernel<<<(2 * SEQ * MLPH + 255) / 256, 256, 0, stream>>>(Psh, Psm, b1v, shb, smb);

  score_kernel<<<SEQ, 256, 0, stream>>>(shb, smb, W2, b2, out);
}

// Round 8
// 2425.329 us; speedup vs baseline: 1.8315x; 1.8315x over previous
//
#include <hip/hip_runtime.h>
#include <stdint.h>

#define SEQ 512
#define HID 512
#define GATES 2048
#define IN0 1088
#define IN1 1024
#define MLPH 100

// ---------------- zero (sync slots) ----------------
__global__ void zero_kernel(uint4* __restrict__ p, int n) {
  int i = blockIdx.x * blockDim.x + threadIdx.x;
  uint4 z = {0u, 0u, 0u, 0u};
  if (i < n) p[i] = z;
}

// ---------------- embedding gather + concat ----------------
__global__ __launch_bounds__(256) void embed_kernel(
    const int* __restrict__ widx, const int* __restrict__ pidx,
    const float* __restrict__ wemb, const float* __restrict__ pemb,
    float* __restrict__ out) {
  int t = blockIdx.x, tid = threadIdx.x;
  const float4* wsrc = (const float4*)(wemb + (size_t)widx[t] * 1024);
  float4* dst = (float4*)(out + (size_t)t * IN0);
  dst[tid] = wsrc[tid];                       // 256 float4 = 1024 floats
  if (tid < 16) {
    const float4* psrc = (const float4*)(pemb + (size_t)pidx[t] * 64);
    dst[256 + tid] = psrc[tid];               // 64 floats
  }
}

// ---------------- compiler-proof double exp: range-reduced Taylor ----------------
__device__ __forceinline__ double exp_d(double x) {
  const double LOG2E = 1.4426950408889634074;
  const double LN2HI = 6.93147180369123816490e-01;
  const double LN2LO = 1.90821492927058770002e-10;
  double t = x * LOG2E;
  double n = floor(t + 0.5);
  double r = x - n * LN2HI;
  r = r - n * LN2LO;
  double p = 2.50521083854417187751e-08;   // 1/11!
  p = p * r + 2.75573192239858906526e-07;  // 1/10!
  p = p * r + 2.75573192239858925110e-06;  // 1/9!
  p = p * r + 2.48015873015873015873e-05;  // 1/8!
  p = p * r + 1.98412698412698412698e-04;  // 1/7!
  p = p * r + 1.38888888888888888889e-03;  // 1/6!
  p = p * r + 8.33333333333333333333e-03;  // 1/5!
  p = p * r + 4.16666666666666666667e-02;  // 1/4!
  p = p * r + 1.66666666666666666667e-01;  // 1/3!
  p = p * r + 0.5;
  p = p * r + 1.0;
  p = p * r + 1.0;
  long long ni = (long long)n;
  double s = __longlong_as_double((unsigned long long)(ni + 1023) << 52);
  return p * s;
}

// ---------------- xw GEMM: fp32 in/out, fp64 K-accumulation (deterministic) ----------------
__global__ __launch_bounds__(256) void gemm_facc(
    const float* __restrict__ A, const float* __restrict__ Bt,
    const float* __restrict__ bias, float* __restrict__ C,
    int M, int N, int K) {
  int ntiles = N >> 6;
  int bid = blockIdx.x;
  int mt = bid / ntiles, nt = bid - mt * ntiles;

  __shared__ float As[16][68];
  __shared__ float Bs[16][68];
  int tid = threadIdx.x;
  int tx = tid & 15, ty = tid >> 4;
  int m0 = mt << 6, n0 = nt << 6;

  int lk4 = tid & 3;
  int lrow = tid >> 2;
  const float* Ap = A + (size_t)(m0 + lrow) * K + lk4 * 4;
  const float* Bp = Bt + (size_t)(n0 + lrow) * K + lk4 * 4;

  double acc[4][4];
#pragma unroll
  for (int i = 0; i < 4; ++i)
#pragma unroll
    for (int j = 0; j < 4; ++j) acc[i][j] = 0.0;

  for (int kk = 0; kk < K; kk += 16) {
    float4 av = *(const float4*)(Ap + kk);
    float4 bv = *(const float4*)(Bp + kk);
    int kbase = lk4 * 4;
    As[kbase + 0][lrow] = av.x; As[kbase + 1][lrow] = av.y;
    As[kbase + 2][lrow] = av.z; As[kbase + 3][lrow] = av.w;
    Bs[kbase + 0][lrow] = bv.x; Bs[kbase + 1][lrow] = bv.y;
    Bs[kbase + 2][lrow] = bv.z; Bs[kbase + 3][lrow] = bv.w;
    __syncthreads();
#pragma unroll
    for (int k = 0; k < 16; ++k) {
      float a[4], b[4];
      *(float4*)a = *(const float4*)&As[k][ty << 2];
      *(float4*)b = *(const float4*)&Bs[k][tx << 2];
#pragma unroll
      for (int i = 0; i < 4; ++i)
#pragma unroll
        for (int j = 0; j < 4; ++j) acc[i][j] += (double)a[i] * (double)b[j];
    }
    __syncthreads();
  }

#pragma unroll
  for (int i = 0; i < 4; ++i) {
    int mrow = m0 + (ty << 2) + i;
#pragma unroll
    for (int j = 0; j < 4; ++j) {
      int ncol = n0 + (tx << 2) + j;
      C[(size_t)mrow * N + ncol] = (float)(acc[i][j] + (double)bias[ncol]);
    }
  }
}

// ---------------- MLP projection stage 1: per-K-chunk partials, fp64 accumulation ----------------
__global__ __launch_bounds__(256) void gemm_pd_kernel(
    const float* __restrict__ A, const float* __restrict__ Bt,
    float* __restrict__ Cpart, int M, int N, int K, int ldb, int kSplit) {
  int ntiles = (N + 63) >> 6;
  int mtiles = M >> 6;
  int tilesPer = ntiles * mtiles;
  int bid = blockIdx.x;
  int kchunk = bid / tilesPer;
  int rem = bid - kchunk * tilesPer;
  int mt = rem / ntiles, nt = rem - mt * ntiles;
  int kLen = K / kSplit;
  int k0 = kchunk * kLen;

  __shared__ float As[16][68];
  __shared__ float Bs[16][68];
  int tid = threadIdx.x;
  int tx = tid & 15, ty = tid >> 4;
  int m0 = mt << 6, n0 = nt << 6;

  int lk4 = tid & 3;
  int lrow = tid >> 2;
  const float* Ap = A + (size_t)(m0 + lrow) * K + k0 + lk4 * 4;
  const float* Bp = Bt + (size_t)(n0 + lrow) * ldb + k0 + lk4 * 4;
  bool bvalid = (n0 + lrow) < N;

  double acc[4][4];
#pragma unroll
  for (int i = 0; i < 4; ++i)
#pragma unroll
    for (int j = 0; j < 4; ++j) acc[i][j] = 0.0;

  for (int kk = 0; kk < kLen; kk += 16) {
    float4 av = *(const float4*)(Ap + kk);
    float4 bv;
    if (bvalid) bv = *(const float4*)(Bp + kk);
    else { bv.x = bv.y = bv.z = bv.w = 0.f; }
    int kbase = lk4 * 4;
    As[kbase + 0][lrow] = av.x; As[kbase + 1][lrow] = av.y;
    As[kbase + 2][lrow] = av.z; As[kbase + 3][lrow] = av.w;
    Bs[kbase + 0][lrow] = bv.x; Bs[kbase + 1][lrow] = bv.y;
    Bs[kbase + 2][lrow] = bv.z; Bs[kbase + 3][lrow] = bv.w;
    __syncthreads();
#pragma unroll
    for (int k = 0; k < 16; ++k) {
      float a[4], b[4];
      *(float4*)a = *(const float4*)&As[k][ty << 2];
      *(float4*)b = *(const float4*)&Bs[k][tx << 2];
#pragma unroll
      for (int i = 0; i < 4; ++i)
#pragma unroll
        for (int j = 0; j < 4; ++j) acc[i][j] += (double)a[i] * (double)b[j];
    }
    __syncthreads();
  }

#pragma unroll
  for (int i = 0; i < 4; ++i) {
    int mrow = m0 + (ty << 2) + i;
#pragma unroll
    for (int j = 0; j < 4; ++j) {
      int ncol = n0 + (tx << 2) + j;
      if (ncol < N)
        Cpart[((size_t)kchunk * M + mrow) * N + ncol] = (float)acc[i][j];
    }
  }
}

// ---------------- MLP projection stage 2: fixed-order reduce over kSplit chunks ----------------
__global__ __launch_bounds__(256) void mlp_reduce_kernel(
    const float* __restrict__ Psh, const float* __restrict__ Psm,
    const float* __restrict__ b1, float* __restrict__ sh, float* __restrict__ sm) {
  int idx = blockIdx.x * 256 + threadIdx.x;
  const int HALF = SEQ * MLPH;  // 51200
  if (idx < HALF) {
    float s = 0.f;
#pragma unroll
    for (int c = 0; c < 8; ++c) s += Psh[(size_t)c * HALF + idx];
    sh[idx] = s;
  } else if (idx < 2 * HALF) {
    int j = idx - HALF;
    float s = 0.f;
#pragma unroll
    for (int c = 0; c < 8; ++c) s += Psm[(size_t)c * HALF + j];
    sm[j] = s + b1[j % MLPH];
  }
}

// ---------------- biLSTM layer scan ----------------
// R8 = R6 compute structure + R1/R2 wide poll.
// grid = 128 WGs x 256 threads. WG 0..63 forward, 64..127 backward; each owns 8 h-rows.
// W tile (32 gate rows x 512) fp32 in LDS (64 KB), loaded once.
// Poll: ALL 256 threads watch 2 slots each, both loads issued per iteration
// (4x detection parallelism vs R6/R7's 64-thread poll — R1 evidence).
// Arithmetic bit-identical to R6: same {k*128+cg*4} partial grouping, same
// fp64 reduce order, same exp_d tail, fp64 c-state.
__global__ __launch_bounds__(256, 1) void scan_kernel(
    const float* __restrict__ whh_f, const float* __restrict__ whh_b,
    const float* __restrict__ xw_f, const float* __restrict__ xw_b,
    float* __restrict__ hout, unsigned long long* __restrict__ slots) {
  int wg = blockIdx.x;
  int dir = wg >> 6;
  int lw = wg & 63;
  int r0 = lw << 3;                 // first owned h row
  const float* whh = dir ? whh_b : whh_f;
  const float* xw = dir ? xw_b : xw_f;
  unsigned long long* slotbase = slots + (size_t)dir * 1024;  // [buf2][512]

  int tid = threadIdx.x;
  int cg = tid & 31;                // col group
  int rg = tid >> 5;                // row group 0..7 (4 rows each)

  __shared__ __align__(16) float Wl[32][512];   // 64 KB
  __shared__ __align__(16) float hl[512];       // 2 KB
  __shared__ float part[32][33];                // 4.2 KB

  // load W tile: local row -> global row (row>>3)*512 + r0 + (row&7)
  {
    float4* Wl4 = (float4*)&Wl[0][0];
#pragma unroll
    for (int i = 0; i < 16; ++i) {
      int fid = i * 256 + tid;        // 0..4095 float4s
      int row = fid >> 7;             // 0..31
      int c4 = fid & 127;
      int grow = ((row >> 3) << 9) + r0 + (row & 7);
      Wl4[row * 128 + c4] = *(const float4*)(whh + (size_t)grow * 512 + c4 * 4);
    }
  }
  __syncthreads();

  double cstate = 0.0;  // live in lanes 0..7 of wave 0

  for (int s = 0; s < SEQ; ++s) {
    int t = dir ? (SEQ - 1 - s) : s;

    // xw prefetch: lane j<32 takes gate row j (gate=j>>3, idx=j&7) — overlaps poll
    float xwv = 0.f;
    if (tid < 32)
      xwv = xw[(size_t)t * GATES + ((tid >> 3) << 9) + r0 + (tid & 7)];

    // obtain h_{s-1}: ALL 256 threads poll 2 slots each (wide detection)
    if (s == 0) {
      for (int i = tid; i < 512; i += 256) hl[i] = 0.f;
    } else {
      unsigned long long* sb = slotbase + (size_t)((s + 1) & 1) * 512;
      unsigned long long expect = (unsigned long long)s;
      int i0 = tid * 2;
      unsigned long long v0, v1;
      do {  // both loads in flight each iteration — one latency, not two
        v0 = __hip_atomic_load(&sb[i0], __ATOMIC_RELAXED, __HIP_MEMORY_SCOPE_AGENT);
        v1 = __hip_atomic_load(&sb[i0 + 1], __ATOMIC_RELAXED, __HIP_MEMORY_SCOPE_AGENT);
      } while ((v0 >> 32) != expect || (v1 >> 32) != expect);
      hl[i0] = __uint_as_float((unsigned)v0);
      hl[i0 + 1] = __uint_as_float((unsigned)v1);
    }
    __syncthreads();  // B1

    // matvec: thread (cg,rg): rows rg*4..+3, cols {k*128 + cg*4..+3, k=0..3}
    // all LDS accesses lane-consecutive 16B -> conflict-free (R6-identical)
    {
      const float4* hl4 = (const float4*)hl;
      float4 hv0 = hl4[cg];
      float4 hv1 = hl4[32 + cg];
      float4 hv2 = hl4[64 + cg];
      float4 hv3 = hl4[96 + cg];
      const float4* Wl4 = (const float4*)&Wl[0][0];
#pragma unroll
      for (int rr = 0; rr < 4; ++rr) {
        int r = (rg << 2) + rr;
        const float4* wrow = Wl4 + r * 128;
        float4 w0 = wrow[cg], w1 = wrow[32 + cg], w2 = wrow[64 + cg], w3 = wrow[96 + cg];
        float a = w0.x * hv0.x + w0.y * hv0.y + w0.z * hv0.z + w0.w * hv0.w
                + w1.x * hv1.x + w1.y * hv1.y + w1.z * hv1.z + w1.w * hv1.w
                + w2.x * hv2.x + w2.y * hv2.y + w2.z * hv2.z + w2.w * hv2.w
                + w3.x * hv3.x + w3.y * hv3.y + w3.z * hv3.z + w3.w * hv3.w;
        part[r][cg] = a;
      }
    }
    __syncthreads();  // B2

    // wave 0 lanes 0..31: fp64 fixed-order reduce; per-lane exp_d; gather; gates
    if (tid < 32) {
      double z = (double)xwv;
#pragma unroll
      for (int g = 0; g < 32; ++g) z += (double)part[tid][g];
      double ev = ((tid >> 3) == 2) ? exp_d(2.0 * z) : exp_d(-z);
      // lane j<8 needs: e_i (lane j), e_f (j+8), e_g (j+16), e_o (j+24)
      double e_f = __shfl(ev, tid + 8);
      double e_g = __shfl(ev, tid + 16);
      double e_o = __shfl(ev, tid + 24);
      if (tid < 8) {
        double ig = 1.0 / (1.0 + ev);
        double fg = 1.0 / (1.0 + e_f);
        double og = 1.0 / (1.0 + e_o);
        double gg = 1.0 - 2.0 / (e_g + 1.0);       // tanh(z_g)
        cstate = fg * cstate + ig * gg;
        double e2c = exp_d(2.0 * cstate);
        double hd = og * (1.0 - 2.0 / (e2c + 1.0)); // og * tanh(c)
        float h = (float)hd;
        // publish FIRST; hout store after
        unsigned long long pub =
            (((unsigned long long)(s + 1)) << 32) | (unsigned long long)__float_as_uint(h);
        __hip_atomic_store(&slotbase[(size_t)(s & 1) * 512 + r0 + tid], pub,
                           __ATOMIC_RELAXED, __HIP_MEMORY_SCOPE_AGENT);
        hout[(size_t)t * IN1 + dir * 512 + r0 + tid] = h;
      }
    }
    // no trailing barrier: hl(s+1) poll-writes happen only after B2(s)
  }
}

// ---------------- pairwise MLP score + column softmax ----------------
#define SCH 128
__global__ __launch_bounds__(256) void score_kernel(
    const float* __restrict__ sh, const float* __restrict__ smb,
    const float* __restrict__ W2v, const float* __restrict__ b2,
    float* __restrict__ out) {
  int m = blockIdx.x;
  int tid = threadIdx.x;
  __shared__ float smv[MLPH];
  __shared__ float w2s[MLPH];
  __shared__ float shc[SCH][101];
  __shared__ float sbuf[512];
  __shared__ float rbuf[256];

  if (tid < MLPH) {
    smv[tid] = smb[(size_t)m * MLPH + tid];
    w2s[tid] = W2v[tid];
  }
  __syncthreads();

  int row = tid >> 1, half = tid & 1;
  float bb = b2[0];
  for (int ch = 0; ch < 4; ++ch) {
    const float* src = sh + (size_t)ch * SCH * MLPH;
    for (int i = tid; i < SCH * MLPH; i += 256) {
      int r = i / MLPH, c = i - r * MLPH;
      shc[r][c] = src[i];
    }
    __syncthreads();
    float acc = 0.f;
#pragma unroll
    for (int k = 0; k < 50; ++k) {
      int kk = half * 50 + k;
      float x = shc[row][kk] + smv[kk];
      float e = __expf(x + x);
      float th = 1.f - 2.f / (e + 1.f);
      acc += w2s[kk] * th;
    }
    acc += __shfl_xor(acc, 1);
    if (half == 0) sbuf[ch * SCH + row] = acc + bb;
    __syncthreads();
  }

  float v0 = sbuf[tid], v1 = sbuf[tid + 256];
  rbuf[tid] = fmaxf(v0, v1);
  __syncthreads();
  for (int off = 128; off > 0; off >>= 1) {
    if (tid < off) rbuf[tid] = fmaxf(rbuf[tid], rbuf[tid + off]);
    __syncthreads();
  }
  float mx = rbuf[0];
  __syncthreads();
  float e0 = __expf(v0 - mx), e1 = __expf(v1 - mx);
  rbuf[tid] = e0 + e1;
  __syncthreads();
  for (int off = 128; off > 0; off >>= 1) {
    if (tid < off) rbuf[tid] += rbuf[tid + off];
    __syncthreads();
  }
  float inv = 1.f / rbuf[0];
  out[(size_t)tid * 512 + m] = e0 * inv;
  out[(size_t)(tid + 256) * 512 + m] = e1 * inv;
}

// ---------------- launch ----------------
extern "C" void kernel_launch(void* const* d_in, const int* in_sizes, int n_in,
                              void* d_out, int out_size, void* d_ws, size_t ws_size,
                              hipStream_t stream) {
  const int* widx = (const int*)d_in[0];
  const int* pidx = (const int*)d_in[1];
  const float* wemb = (const float*)d_in[2];
  const float* pemb = (const float*)d_in[3];
  const float* wih0f = (const float*)d_in[4];
  const float* whh0f = (const float*)d_in[5];
  const float* b0f = (const float*)d_in[6];
  const float* wih0b = (const float*)d_in[7];
  const float* whh0b = (const float*)d_in[8];
  const float* b0b = (const float*)d_in[9];
  const float* wih1f = (const float*)d_in[10];
  const float* whh1f = (const float*)d_in[11];
  const float* b1f = (const float*)d_in[12];
  const float* wih1b = (const float*)d_in[13];
  const float* whh1b = (const float*)d_in[14];
  const float* b1b = (const float*)d_in[15];
  const float* W1 = (const float*)d_in[16];
  const float* b1v = (const float*)d_in[17];
  const float* W2 = (const float*)d_in[18];
  const float* b2 = (const float*)d_in[19];
  float* out = (float*)d_out;

  // ---- workspace layout: 18.53 MB (unchanged) ----
  float* ws = (float*)d_ws;
  float* embeds = ws;                          // 557,056
  float* xwf = embeds + 557056;                // 1,048,576
  float* xwb = xwf + 1048576;                  // 1,048,576
  float* h0 = xwb + 1048576;                   // 524,288
  float* h1 = h0 + 524288;                     // 524,288
  float* Psh = h1 + 524288;                    // 409,600
  float* Psm = Psh + 409600;                   // 409,600
  float* shb = Psm + 409600;                   // 51,200
  float* smb = shb + 51200;                    // 51,200
  unsigned long long* slots0 = (unsigned long long*)(smb + 51200);  // 2048 u64
  unsigned long long* slots1 = slots0 + 2048;                       // 2048 u64
  size_t total_bytes = (size_t)4624384 * 4 + 4096ull * 8;
  if (ws_size < total_bytes) return;

  // zero sync slots (4096 u64 = 32 KB)
  zero_kernel<<<8, 256, 0, stream>>>((uint4*)slots0, 4096 * 8 / 16);

  embed_kernel<<<SEQ, 256, 0, stream>>>(widx, pidx, wemb, pemb, embeds);

  // layer-0 input projections: [512,1088] @ [2048,1088]^T (fp64 accum, fp32 store)
  gemm_facc<<<8 * 32, 256, 0, stream>>>(embeds, wih0f, b0f, xwf, SEQ, GATES, IN0);
  gemm_facc<<<8 * 32, 256, 0, stream>>>(embeds, wih0b, b0b, xwb, SEQ, GATES, IN0);

  scan_kernel<<<128, 256, 0, stream>>>(whh0f, whh0b, xwf, xwb, h0, slots0);

  // layer-1 input projections: [512,1024] @ [2048,1024]^T
  gemm_facc<<<8 * 32, 256, 0, stream>>>(h0, wih1f, b1f, xwf, SEQ, GATES, IN1);
  gemm_facc<<<8 * 32, 256, 0, stream>>>(h0, wih1b, b1b, xwb, SEQ, GATES, IN1);

  scan_kernel<<<128, 256, 0, stream>>>(whh1f, whh1b, xwf, xwb, h1, slots1);

  // MLP projections: deterministic split-K=8, fp64-accumulated partials + fixed-order reduce
  gemm_pd_kernel<<<8 * 8 * 2, 256, 0, stream>>>(h1, W1, Psh, SEQ, MLPH, IN1, 2048, 8);
  gemm_pd_kernel<<<8 * 8 * 2, 256, 0, stream>>>(h1, W1 + 1024, Psm, SEQ, MLPH, IN1, 2048, 8);
  mlp_reduce_kernel<<<(2 * SEQ * MLPH + 255) / 256, 256, 0, stream>>>(Psh, Psm, b1v, shb, smb);

  score_kernel<<<SEQ, 256, 0, stream>>>(shb, smb, W2, b2, out);
}

// Round 9
// 2300.140 us; speedup vs baseline: 1.9312x; 1.0544x over previous
//
#include <hip/hip_runtime.h>
#include <stdint.h>

#define SEQ 512
#define HID 512
#define GATES 2048
#define IN0 1088
#define IN1 1024
#define MLPH 100

// ---------------- zero (sync slots) ----------------
__global__ void zero_kernel(uint4* __restrict__ p, int n) {
  int i = blockIdx.x * blockDim.x + threadIdx.x;
  uint4 z = {0u, 0u, 0u, 0u};
  if (i < n) p[i] = z;
}

// ---------------- embedding gather + concat ----------------
__global__ __launch_bounds__(256) void embed_kernel(
    const int* __restrict__ widx, const int* __restrict__ pidx,
    const float* __restrict__ wemb, const float* __restrict__ pemb,
    float* __restrict__ out) {
  int t = blockIdx.x, tid = threadIdx.x;
  const float4* wsrc = (const float4*)(wemb + (size_t)widx[t] * 1024);
  float4* dst = (float4*)(out + (size_t)t * IN0);
  dst[tid] = wsrc[tid];                       // 256 float4 = 1024 floats
  if (tid < 16) {
    const float4* psrc = (const float4*)(pemb + (size_t)pidx[t] * 64);
    dst[256 + tid] = psrc[tid];               // 64 floats
  }
}

// ---------------- compiler-proof double exp: range-reduced Taylor ----------------
__device__ __forceinline__ double exp_d(double x) {
  const double LOG2E = 1.4426950408889634074;
  const double LN2HI = 6.93147180369123816490e-01;
  const double LN2LO = 1.90821492927058770002e-10;
  double t = x * LOG2E;
  double n = floor(t + 0.5);
  double r = x - n * LN2HI;
  r = r - n * LN2LO;
  double p = 2.50521083854417187751e-08;   // 1/11!
  p = p * r + 2.75573192239858906526e-07;  // 1/10!
  p = p * r + 2.75573192239858925110e-06;  // 1/9!
  p = p * r + 2.48015873015873015873e-05;  // 1/8!
  p = p * r + 1.98412698412698412698e-04;  // 1/7!
  p = p * r + 1.38888888888888888889e-03;  // 1/6!
  p = p * r + 8.33333333333333333333e-03;  // 1/5!
  p = p * r + 4.16666666666666666667e-02;  // 1/4!
  p = p * r + 1.66666666666666666667e-01;  // 1/3!
  p = p * r + 0.5;
  p = p * r + 1.0;
  p = p * r + 1.0;
  long long ni = (long long)n;
  double s = __longlong_as_double((unsigned long long)(ni + 1023) << 52);
  return p * s;
}

// ---------------- xw GEMM: fp32 in/out, fp64 K-accumulation (deterministic) ----------------
__global__ __launch_bounds__(256) void gemm_facc(
    const float* __restrict__ A, const float* __restrict__ Bt,
    const float* __restrict__ bias, float* __restrict__ C,
    int M, int N, int K) {
  int ntiles = N >> 6;
  int bid = blockIdx.x;
  int mt = bid / ntiles, nt = bid - mt * ntiles;

  __shared__ float As[16][68];
  __shared__ float Bs[16][68];
  int tid = threadIdx.x;
  int tx = tid & 15, ty = tid >> 4;
  int m0 = mt << 6, n0 = nt << 6;

  int lk4 = tid & 3;
  int lrow = tid >> 2;
  const float* Ap = A + (size_t)(m0 + lrow) * K + lk4 * 4;
  const float* Bp = Bt + (size_t)(n0 + lrow) * K + lk4 * 4;

  double acc[4][4];
#pragma unroll
  for (int i = 0; i < 4; ++i)
#pragma unroll
    for (int j = 0; j < 4; ++j) acc[i][j] = 0.0;

  for (int kk = 0; kk < K; kk += 16) {
    float4 av = *(const float4*)(Ap + kk);
    float4 bv = *(const float4*)(Bp + kk);
    int kbase = lk4 * 4;
    As[kbase + 0][lrow] = av.x; As[kbase + 1][lrow] = av.y;
    As[kbase + 2][lrow] = av.z; As[kbase + 3][lrow] = av.w;
    Bs[kbase + 0][lrow] = bv.x; Bs[kbase + 1][lrow] = bv.y;
    Bs[kbase + 2][lrow] = bv.z; Bs[kbase + 3][lrow] = bv.w;
    __syncthreads();
#pragma unroll
    for (int k = 0; k < 16; ++k) {
      float a[4], b[4];
      *(float4*)a = *(const float4*)&As[k][ty << 2];
      *(float4*)b = *(const float4*)&Bs[k][tx << 2];
#pragma unroll
      for (int i = 0; i < 4; ++i)
#pragma unroll
        for (int j = 0; j < 4; ++j) acc[i][j] += (double)a[i] * (double)b[j];
    }
    __syncthreads();
  }

#pragma unroll
  for (int i = 0; i < 4; ++i) {
    int mrow = m0 + (ty << 2) + i;
#pragma unroll
    for (int j = 0; j < 4; ++j) {
      int ncol = n0 + (tx << 2) + j;
      C[(size_t)mrow * N + ncol] = (float)(acc[i][j] + (double)bias[ncol]);
    }
  }
}

// ---------------- MLP projection stage 1: per-K-chunk partials, fp64 accumulation ----------------
__global__ __launch_bounds__(256) void gemm_pd_kernel(
    const float* __restrict__ A, const float* __restrict__ Bt,
    float* __restrict__ Cpart, int M, int N, int K, int ldb, int kSplit) {
  int ntiles = (N + 63) >> 6;
  int mtiles = M >> 6;
  int tilesPer = ntiles * mtiles;
  int bid = blockIdx.x;
  int kchunk = bid / tilesPer;
  int rem = bid - kchunk * tilesPer;
  int mt = rem / ntiles, nt = rem - mt * ntiles;
  int kLen = K / kSplit;
  int k0 = kchunk * kLen;

  __shared__ float As[16][68];
  __shared__ float Bs[16][68];
  int tid = threadIdx.x;
  int tx = tid & 15, ty = tid >> 4;
  int m0 = mt << 6, n0 = nt << 6;

  int lk4 = tid & 3;
  int lrow = tid >> 2;
  const float* Ap = A + (size_t)(m0 + lrow) * K + k0 + lk4 * 4;
  const float* Bp = Bt + (size_t)(n0 + lrow) * ldb + k0 + lk4 * 4;
  bool bvalid = (n0 + lrow) < N;

  double acc[4][4];
#pragma unroll
  for (int i = 0; i < 4; ++i)
#pragma unroll
    for (int j = 0; j < 4; ++j) acc[i][j] = 0.0;

  for (int kk = 0; kk < kLen; kk += 16) {
    float4 av = *(const float4*)(Ap + kk);
    float4 bv;
    if (bvalid) bv = *(const float4*)(Bp + kk);
    else { bv.x = bv.y = bv.z = bv.w = 0.f; }
    int kbase = lk4 * 4;
    As[kbase + 0][lrow] = av.x; As[kbase + 1][lrow] = av.y;
    As[kbase + 2][lrow] = av.z; As[kbase + 3][lrow] = av.w;
    Bs[kbase + 0][lrow] = bv.x; Bs[kbase + 1][lrow] = bv.y;
    Bs[kbase + 2][lrow] = bv.z; Bs[kbase + 3][lrow] = bv.w;
    __syncthreads();
#pragma unroll
    for (int k = 0; k < 16; ++k) {
      float a[4], b[4];
      *(float4*)a = *(const float4*)&As[k][ty << 2];
      *(float4*)b = *(const float4*)&Bs[k][tx << 2];
#pragma unroll
      for (int i = 0; i < 4; ++i)
#pragma unroll
        for (int j = 0; j < 4; ++j) acc[i][j] += (double)a[i] * (double)b[j];
    }
    __syncthreads();
  }

#pragma unroll
  for (int i = 0; i < 4; ++i) {
    int mrow = m0 + (ty << 2) + i;
#pragma unroll
    for (int j = 0; j < 4; ++j) {
      int ncol = n0 + (tx << 2) + j;
      if (ncol < N)
        Cpart[((size_t)kchunk * M + mrow) * N + ncol] = (float)acc[i][j];
    }
  }
}

// ---------------- MLP projection stage 2: fixed-order reduce over kSplit chunks ----------------
__global__ __launch_bounds__(256) void mlp_reduce_kernel(
    const float* __restrict__ Psh, const float* __restrict__ Psm,
    const float* __restrict__ b1, float* __restrict__ sh, float* __restrict__ sm) {
  int idx = blockIdx.x * 256 + threadIdx.x;
  const int HALF = SEQ * MLPH;  // 51200
  if (idx < HALF) {
    float s = 0.f;
#pragma unroll
    for (int c = 0; c < 8; ++c) s += Psh[(size_t)c * HALF + idx];
    sh[idx] = s;
  } else if (idx < 2 * HALF) {
    int j = idx - HALF;
    float s = 0.f;
#pragma unroll
    for (int c = 0; c < 8; ++c) s += Psm[(size_t)c * HALF + j];
    sm[j] = s + b1[j % MLPH];
  }
}

// ---------------- biLSTM layer scan ----------------
// R9 = R8 + W in VGPRs (kills the 64KB LDS-W read stream on the B1->B2
// critical path: 20 b128 LDS reads/thread/step -> 4).
// grid = 128 WGs x 256 threads. WG 0..63 forward, 64..127 backward; each owns
// 8 h-rows. Thread (cg,rg) holds W for its 4 rows x 16 cols in registers
// (64 fp32, fully static indexing). Wide poll: all 256 threads watch 2 slots.
// Arithmetic bit-identical to R6/R8 -> absmax must be exactly 7.629395e-06.
__global__ __launch_bounds__(256, 1) void scan_kernel(
    const float* __restrict__ whh_f, const float* __restrict__ whh_b,
    const float* __restrict__ xw_f, const float* __restrict__ xw_b,
    float* __restrict__ hout, unsigned long long* __restrict__ slots) {
  int wg = blockIdx.x;
  int dir = wg >> 6;
  int lw = wg & 63;
  int r0 = lw << 3;                 // first owned h row
  const float* whh = dir ? whh_b : whh_f;
  const float* xw = dir ? xw_b : xw_f;
  unsigned long long* slotbase = slots + (size_t)dir * 1024;  // [buf2][512]

  int tid = threadIdx.x;
  int cg = tid & 31;                // col group
  int rg = tid >> 5;                // row group 0..7 (4 rows each)

  __shared__ __align__(16) float hl[512];       // 2 KB
  __shared__ float part[32][33];                // 4.2 KB

  // W into registers: Wr[rr][k*4+j] = whh[grow(rg*4+rr)][k*128 + cg*4 + j]
  // grow(r) = (r>>3)*512 + r0 + (r&7)  (r = local row 0..31)
  float Wr[4][16];
#pragma unroll
  for (int rr = 0; rr < 4; ++rr) {
    int r = (rg << 2) + rr;
    int grow = ((r >> 3) << 9) + r0 + (r & 7);
    const float* src = whh + (size_t)grow * 512 + cg * 4;
#pragma unroll
    for (int k = 0; k < 4; ++k) {
      float4 v = *(const float4*)(src + k * 128);
      Wr[rr][k * 4 + 0] = v.x; Wr[rr][k * 4 + 1] = v.y;
      Wr[rr][k * 4 + 2] = v.z; Wr[rr][k * 4 + 3] = v.w;
    }
  }

  double cstate = 0.0;  // live in lanes 0..7 of wave 0

  for (int s = 0; s < SEQ; ++s) {
    int t = dir ? (SEQ - 1 - s) : s;

    // xw prefetch: lane j<32 takes gate row j (gate=j>>3, idx=j&7) — overlaps poll
    float xwv = 0.f;
    if (tid < 32)
      xwv = xw[(size_t)t * GATES + ((tid >> 3) << 9) + r0 + (tid & 7)];

    // obtain h_{s-1}: ALL 256 threads poll 2 slots each (wide detection)
    if (s == 0) {
      for (int i = tid; i < 512; i += 256) hl[i] = 0.f;
    } else {
      unsigned long long* sb = slotbase + (size_t)((s + 1) & 1) * 512;
      unsigned long long expect = (unsigned long long)s;
      int i0 = tid * 2;
      unsigned long long v0, v1;
      do {  // both loads in flight each iteration — one latency, not two
        v0 = __hip_atomic_load(&sb[i0], __ATOMIC_RELAXED, __HIP_MEMORY_SCOPE_AGENT);
        v1 = __hip_atomic_load(&sb[i0 + 1], __ATOMIC_RELAXED, __HIP_MEMORY_SCOPE_AGENT);
      } while ((v0 >> 32) != expect || (v1 >> 32) != expect);
      hl[i0] = __uint_as_float((unsigned)v0);
      hl[i0 + 1] = __uint_as_float((unsigned)v1);
    }
    __syncthreads();  // B1

    // matvec: thread (cg,rg): rows rg*4..+3, cols {k*128 + cg*4..+3, k=0..3}
    // W from registers; only h comes from LDS (4 b128 reads)
    {
      const float4* hl4 = (const float4*)hl;
      float4 hv0 = hl4[cg];
      float4 hv1 = hl4[32 + cg];
      float4 hv2 = hl4[64 + cg];
      float4 hv3 = hl4[96 + cg];
#pragma unroll
      for (int rr = 0; rr < 4; ++rr) {
        int r = (rg << 2) + rr;
        float a = Wr[rr][0]  * hv0.x + Wr[rr][1]  * hv0.y + Wr[rr][2]  * hv0.z + Wr[rr][3]  * hv0.w
                + Wr[rr][4]  * hv1.x + Wr[rr][5]  * hv1.y + Wr[rr][6]  * hv1.z + Wr[rr][7]  * hv1.w
                + Wr[rr][8]  * hv2.x + Wr[rr][9]  * hv2.y + Wr[rr][10] * hv2.z + Wr[rr][11] * hv2.w
                + Wr[rr][12] * hv3.x + Wr[rr][13] * hv3.y + Wr[rr][14] * hv3.z + Wr[rr][15] * hv3.w;
        part[r][cg] = a;
      }
    }
    __syncthreads();  // B2

    // wave 0 lanes 0..31: fp64 fixed-order reduce; per-lane exp_d; gather; gates
    if (tid < 32) {
      double z = (double)xwv;
#pragma unroll
      for (int g = 0; g < 32; ++g) z += (double)part[tid][g];
      double ev = ((tid >> 3) == 2) ? exp_d(2.0 * z) : exp_d(-z);
      // lane j<8 needs: e_i (lane j), e_f (j+8), e_g (j+16), e_o (j+24)
      double e_f = __shfl(ev, tid + 8);
      double e_g = __shfl(ev, tid + 16);
      double e_o = __shfl(ev, tid + 24);
      if (tid < 8) {
        double ig = 1.0 / (1.0 + ev);
        double fg = 1.0 / (1.0 + e_f);
        double og = 1.0 / (1.0 + e_o);
        double gg = 1.0 - 2.0 / (e_g + 1.0);       // tanh(z_g)
        cstate = fg * cstate + ig * gg;
        double e2c = exp_d(2.0 * cstate);
        double hd = og * (1.0 - 2.0 / (e2c + 1.0)); // og * tanh(c)
        float h = (float)hd;
        // publish FIRST; hout store after
        unsigned long long pub =
            (((unsigned long long)(s + 1)) << 32) | (unsigned long long)__float_as_uint(h);
        __hip_atomic_store(&slotbase[(size_t)(s & 1) * 512 + r0 + tid], pub,
                           __ATOMIC_RELAXED, __HIP_MEMORY_SCOPE_AGENT);
        hout[(size_t)t * IN1 + dir * 512 + r0 + tid] = h;
      }
    }
    // no trailing barrier: hl(s+1) poll-writes happen only after B2(s)
  }
}

// ---------------- pairwise MLP score + column softmax ----------------
#define SCH 128
__global__ __launch_bounds__(256) void score_kernel(
    const float* __restrict__ sh, const float* __restrict__ smb,
    const float* __restrict__ W2v, const float* __restrict__ b2,
    float* __restrict__ out) {
  int m = blockIdx.x;
  int tid = threadIdx.x;
  __shared__ float smv[MLPH];
  __shared__ float w2s[MLPH];
  __shared__ float shc[SCH][101];
  __shared__ float sbuf[512];
  __shared__ float rbuf[256];

  if (tid < MLPH) {
    smv[tid] = smb[(size_t)m * MLPH + tid];
    w2s[tid] = W2v[tid];
  }
  __syncthreads();

  int row = tid >> 1, half = tid & 1;
  float bb = b2[0];
  for (int ch = 0; ch < 4; ++ch) {
    const float* src = sh + (size_t)ch * SCH * MLPH;
    for (int i = tid; i < SCH * MLPH; i += 256) {
      int r = i / MLPH, c = i - r * MLPH;
      shc[r][c] = src[i];
    }
    __syncthreads();
    float acc = 0.f;
#pragma unroll
    for (int k = 0; k < 50; ++k) {
      int kk = half * 50 + k;
      float x = shc[row][kk] + smv[kk];
      float e = __expf(x + x);
      float th = 1.f - 2.f / (e + 1.f);
      acc += w2s[kk] * th;
    }
    acc += __shfl_xor(acc, 1);
    if (half == 0) sbuf[ch * SCH + row] = acc + bb;
    __syncthreads();
  }

  float v0 = sbuf[tid], v1 = sbuf[tid + 256];
  rbuf[tid] = fmaxf(v0, v1);
  __syncthreads();
  for (int off = 128; off > 0; off >>= 1) {
    if (tid < off) rbuf[tid] = fmaxf(rbuf[tid], rbuf[tid + off]);
    __syncthreads();
  }
  float mx = rbuf[0];
  __syncthreads();
  float e0 = __expf(v0 - mx), e1 = __expf(v1 - mx);
  rbuf[tid] = e0 + e1;
  __syncthreads();
  for (int off = 128; off > 0; off >>= 1) {
    if (tid < off) rbuf[tid] += rbuf[tid + off];
    __syncthreads();
  }
  float inv = 1.f / rbuf[0];
  out[(size_t)tid * 512 + m] = e0 * inv;
  out[(size_t)(tid + 256) * 512 + m] = e1 * inv;
}

// ---------------- launch ----------------
extern "C" void kernel_launch(void* const* d_in, const int* in_sizes, int n_in,
                              void* d_out, int out_size, void* d_ws, size_t ws_size,
                              hipStream_t stream) {
  const int* widx = (const int*)d_in[0];
  const int* pidx = (const int*)d_in[1];
  const float* wemb = (const float*)d_in[2];
  const float* pemb = (const float*)d_in[3];
  const float* wih0f = (const float*)d_in[4];
  const float* whh0f = (const float*)d_in[5];
  const float* b0f = (const float*)d_in[6];
  const float* wih0b = (const float*)d_in[7];
  const float* whh0b = (const float*)d_in[8];
  const float* b0b = (const float*)d_in[9];
  const float* wih1f = (const float*)d_in[10];
  const float* whh1f = (const float*)d_in[11];
  const float* b1f = (const float*)d_in[12];
  const float* wih1b = (const float*)d_in[13];
  const float* whh1b = (const float*)d_in[14];
  const float* b1b = (const float*)d_in[15];
  const float* W1 = (const float*)d_in[16];
  const float* b1v = (const float*)d_in[17];
  const float* W2 = (const float*)d_in[18];
  const float* b2 = (const float*)d_in[19];
  float* out = (float*)d_out;

  // ---- workspace layout: 18.53 MB (unchanged) ----
  float* ws = (float*)d_ws;
  float* embeds = ws;                          // 557,056
  float* xwf = embeds + 557056;                // 1,048,576
  float* xwb = xwf + 1048576;                  // 1,048,576
  float* h0 = xwb + 1048576;                   // 524,288
  float* h1 = h0 + 524288;                     // 524,288
  float* Psh = h1 + 524288;                    // 409,600
  float* Psm = Psh + 409600;                   // 409,600
  float* shb = Psm + 409600;                   // 51,200
  float* smb = shb + 51200;                    // 51,200
  unsigned long long* slots0 = (unsigned long long*)(smb + 51200);  // 2048 u64
  unsigned long long* slots1 = slots0 + 2048;                       // 2048 u64
  size_t total_bytes = (size_t)4624384 * 4 + 4096ull * 8;
  if (ws_size < total_bytes) return;

  // zero sync slots (4096 u64 = 32 KB)
  zero_kernel<<<8, 256, 0, stream>>>((uint4*)slots0, 4096 * 8 / 16);

  embed_kernel<<<SEQ, 256, 0, stream>>>(widx, pidx, wemb, pemb, embeds);

  // layer-0 input projections: [512,1088] @ [2048,1088]^T (fp64 accum, fp32 store)
  gemm_facc<<<8 * 32, 256, 0, stream>>>(embeds, wih0f, b0f, xwf, SEQ, GATES, IN0);
  gemm_facc<<<8 * 32, 256, 0, stream>>>(embeds, wih0b, b0b, xwb, SEQ, GATES, IN0);

  scan_kernel<<<128, 256, 0, stream>>>(whh0f, whh0b, xwf, xwb, h0, slots0);

  // layer-1 input projections: [512,1024] @ [2048,1024]^T
  gemm_facc<<<8 * 32, 256, 0, stream>>>(h0, wih1f, b1f, xwf, SEQ, GATES, IN1);
  gemm_facc<<<8 * 32, 256, 0, stream>>>(h0, wih1b, b1b, xwb, SEQ, GATES, IN1);

  scan_kernel<<<128, 256, 0, stream>>>(whh1f, whh1b, xwf, xwb, h1, slots1);

  // MLP projections: deterministic split-K=8, fp64-accumulated partials + fixed-order reduce
  gemm_pd_kernel<<<8 * 8 * 2, 256, 0, stream>>>(h1, W1, Psh, SEQ, MLPH, IN1, 2048, 8);
  gemm_pd_kernel<<<8 * 8 * 2, 256, 0, stream>>>(h1, W1 + 1024, Psm, SEQ, MLPH, IN1, 2048, 8);
  mlp_reduce_kernel<<<(2 * SEQ * MLPH + 255) / 256, 256, 0, stream>>>(Psh, Psm, b1v, shb, smb);

  score_kernel<<<SEQ, 256, 0, stream>>>(shb, smb, W2, b2, out);
}